// Round 11
// baseline (535.612 us; speedup 1.0000x reference)
//
#include <hip/hip_runtime.h>
#include <hip/hip_bf16.h>
#include <math.h>

#define CIN 128
#define HH 128
#define WW 128
#define HWX (HH*WW)
#define COUT 256
#define NB 4

typedef __attribute__((ext_vector_type(8))) short short8;
typedef __attribute__((ext_vector_type(4))) float f32x4;
typedef __attribute__((ext_vector_type(8))) unsigned short ushort8;

__device__ __forceinline__ unsigned short f2bf(float f) {
    union { float f; unsigned int u; } c; c.f = f;
    unsigned int u = c.u + 0x7FFF + ((c.u >> 16) & 1);   // RNE
    return (unsigned short)(u >> 16);
}

// ---------------------------------------------------------------------------
// Prep (merged: xt + wimg + wcimg).
// Block roles by blockIdx: [0,2048) xt, [2048,3200) wimg, [3200,3344) wcimg.
// ---------------------------------------------------------------------------
__global__ __launch_bounds__(256) void prep_kernel(
    const float* __restrict__ x, const float* __restrict__ wgt,
    const float* __restrict__ offw, const float* __restrict__ modw,
    float* __restrict__ xT, unsigned short* __restrict__ wAi,
    unsigned short* __restrict__ wCi)
{
    const int tid = threadIdx.x;
    const int bxg = blockIdx.x;

    if (bxg < 2048) {
        // ---- xt: NCHW -> NHWC fp32 transpose ----
        __shared__ float ls[32][132];
        const int bz = bxg;                   // b*512 + y*4 + cg
        const int cg = bz & 3;
        const int y  = (bz >> 2) & 127;
        const int b  = bz >> 9;
        {
            int c  = tid >> 3;                // 0..31
            int x0 = (tid & 7) << 4;
            const float* src = x + (((size_t)(b * CIN + (cg << 5) + c)) << 14) + (y << 7) + x0;
#pragma unroll
            for (int k = 0; k < 4; ++k)
                *(f32x4*)&ls[c][x0 + 4 * k] = *(const f32x4*)(src + 4 * k);
        }
        __syncthreads();
        {
            int xc = tid >> 1;
            int h  = tid & 1;
            float v[16];
#pragma unroll
            for (int j = 0; j < 16; ++j) v[j] = ls[h * 16 + j][xc];
            float* dst = xT + ((((size_t)((b << 7) + y) << 7) + xc) << 7) + (cg << 5) + (h << 4);
#pragma unroll
            for (int k = 0; k < 4; ++k) {
                f32x4 t = { v[4 * k], v[4 * k + 1], v[4 * k + 2], v[4 * k + 3] };
                *(f32x4*)(dst + 4 * k) = t;
            }
        }
    } else if (bxg < 3200) {
        // ---- wimg: bf16 A-fragment image for the big GEMM ----
        int i = (bxg - 2048) * 256 + tid;     // < 294912
        int j  = i & 7;
        int l  = (i >> 3) & 63;
        int mt = (i >> 9) & 15;
        int cc = (i >> 13) & 3;
        int kk = i >> 15;
        int o = mt * 16 + (l & 15);
        int c = cc * 32 + (l >> 4) * 8 + j;
        wAi[i] = f2bf(wgt[(o * CIN + c) * 9 + kk]);
    } else {
        // ---- wcimg: bf16 A-fragment image for offset/mod conv ----
        int i = (bxg - 3200) * 256 + tid;     // < 36864
        if (i < 36864) {
            int j   = i & 7;
            int l   = (i >> 3) & 63;
            int mt  = (i >> 9) & 1;
            int q36 = i >> 10;
            int o = mt * 16 + (l & 15);
            int c = ((q36 & 3) << 5) + ((l >> 4) << 3) + j;
            int t = q36 >> 2;
            float v = 0.f;
            if (o < 18)      v = offw[(o * CIN + c) * 9 + t];
            else if (o < 27) v = modw[((o - 18) * CIN + c) * 9 + t];
            wCi[i] = f2bf(v);
        }
    }
}

// ---------------------------------------------------------------------------
// Kernel CT: implicit-GEMM offset/mod conv via MFMA + fused sampling tables.
// (unchanged from R6/R7 -- verified)
// ---------------------------------------------------------------------------
__global__ __launch_bounds__(256) void convtab_kernel(
    const float* __restrict__ xT, const unsigned short* __restrict__ wCi,
    const float* __restrict__ offb, const float* __restrict__ modb,
    unsigned int* __restrict__ pk_out, float4* __restrict__ w4_out)
{
    __shared__ float outs[4][32][33];
    const int tid = threadIdx.x;
    const int wave = tid >> 6;
    const int l = tid & 63;
    const int bid = blockIdx.x;               // b*128 + y
    const int b = bid >> 7;
    const int y = bid & 127;
    const int x0 = wave << 5;
    const float* xb = xT + ((size_t)b << 21);

    f32x4 acc[2][2];
#pragma unroll
    for (int i = 0; i < 2; ++i)
#pragma unroll
        for (int j = 0; j < 2; ++j) acc[i][j] = (f32x4){0.f, 0.f, 0.f, 0.f};

    const int lp = l & 15;
    const int q8 = (l >> 4) << 3;

#pragma unroll 1
    for (int q36 = 0; q36 < 36; ++q36) {
        const int t  = q36 >> 2;
        const int c0 = (q36 & 3) << 5;
        const int ty = t / 3, tx = t - 3 * ty;
        const int yp = y + ty - 1;
        if (yp < 0 || yp >= HH) continue;     // wave-uniform skip

        const unsigned short* ap = wCi + (q36 << 10) + (l << 3);
        short8 af0 = *(const short8*)(ap);
        short8 af1 = *(const short8*)(ap + 512);

        short8 bf[2];
#pragma unroll
        for (int nt = 0; nt < 2; ++nt) {
            int xp = x0 + nt * 16 + lp + tx - 1;
            bool xin = (xp >= 0) && (xp < WW);
            const float* src = xb +
                ((((yp << 7) + (xin ? xp : 0)) << 7) + c0 + q8);
            f32x4 z = {0.f, 0.f, 0.f, 0.f};
            f32x4 lo = xin ? *(const f32x4*)src : z;
            f32x4 hi = xin ? *(const f32x4*)(src + 4) : z;
            union { unsigned int u[4]; short8 s8; } cv;
            asm("v_cvt_pk_bf16_f32 %0, %1, %2" : "=v"(cv.u[0]) : "v"(lo[0]), "v"(lo[1]));
            asm("v_cvt_pk_bf16_f32 %0, %1, %2" : "=v"(cv.u[1]) : "v"(lo[2]), "v"(lo[3]));
            asm("v_cvt_pk_bf16_f32 %0, %1, %2" : "=v"(cv.u[2]) : "v"(hi[0]), "v"(hi[1]));
            asm("v_cvt_pk_bf16_f32 %0, %1, %2" : "=v"(cv.u[3]) : "v"(hi[2]), "v"(hi[3]));
            bf[nt] = cv.s8;
        }
        acc[0][0] = __builtin_amdgcn_mfma_f32_16x16x32_bf16(af0, bf[0], acc[0][0], 0, 0, 0);
        acc[1][0] = __builtin_amdgcn_mfma_f32_16x16x32_bf16(af1, bf[0], acc[1][0], 0, 0, 0);
        acc[0][1] = __builtin_amdgcn_mfma_f32_16x16x32_bf16(af0, bf[1], acc[0][1], 0, 0, 0);
        acc[1][1] = __builtin_amdgcn_mfma_f32_16x16x32_bf16(af1, bf[1], acc[1][1], 0, 0, 0);
    }

    float (*po)[33] = outs[wave];
#pragma unroll
    for (int mt = 0; mt < 2; ++mt)
#pragma unroll
        for (int nt = 0; nt < 2; ++nt)
#pragma unroll
            for (int r = 0; r < 4; ++r)
                po[nt * 16 + lp][mt * 16 + (l >> 4) * 4 + r] = acc[mt][nt][r];

    const int pxe = l & 31;
    const int xw = x0 + pxe;
    const float* pe = &outs[wave][pxe][0];
#pragma unroll 1
    for (int kk = (l >> 5); kk < 9; kk += 2) {
        float oy = pe[2 * kk]     + offb[2 * kk];
        float ox = pe[2 * kk + 1] + offb[2 * kk + 1];
        float mt_ = pe[18 + kk]   + modb[kk];

        float m = 2.f / (1.f + expf(-mt_));
        float py = (float)(y - 1 + kk / 3) + oy;
        float px = (float)(xw - 1 + kk % 3) + ox;
        float y0f = floorf(py), x0f = floorf(px);
        float wy = py - y0f, wx = px - x0f;
        int y0 = (int)y0f, x0i = (int)x0f;
        int y1 = y0 + 1, x1 = x0i + 1;
        float vy0 = (y0 >= 0 && y0 < HH) ? 1.f : 0.f;
        float vy1 = (y1 >= 0 && y1 < HH) ? 1.f : 0.f;
        float vx0 = (x0i >= 0 && x0i < WW) ? 1.f : 0.f;
        float vx1 = (x1 >= 0 && x1 < WW) ? 1.f : 0.f;
        float a  = m * (1.f - wy) * vy0;
        float bb = m * wy * vy1;
        float u  = (1.f - wx) * vx0;
        float vv = wx * vx1;
        int y0c = min(max(y0, 0), HH - 1), y1c = min(max(y1, 0), HH - 1);
        int x0c = min(max(x0i, 0), WW - 1), x1c = min(max(x1, 0), WW - 1);
        int cb = min(max(x0i, 0), WW - 2);
        float wl = ((x0c == cb) ? u : 0.f) + ((x1c == cb) ? vv : 0.f);
        float wr = ((x0c == cb + 1) ? u : 0.f) + ((x1c == cb + 1) ? vv : 0.f);
        unsigned int pkv = (unsigned)y0c | ((unsigned)y1c << 7) |
                           ((unsigned)cb << 14);
        int gid = ((b * 9 + kk) << 14) + (y << 7) + xw;
        pk_out[gid] = pkv;
        w4_out[gid] = make_float4(a * wl, a * wr, bb * wl, bb * wr);
    }
}

// ---------------------------------------------------------------------------
// Kernel F (R11): fused gather->MFMA GEMM, occupancy + pipeline round.
// R10 counters: conflicts 0 (fixed), but Occupancy 19% / MfmaUtil 16% /
// VALU 34% / HBM 12% -- latency-bound at 2 blocks/CU. Changes:
//  (1) 32-px blocks (grid 2048): acc[4][2], Blds[2][4][2][512] (16 KB),
//      tables 288 entries -> ~22 KB LDS; __launch_bounds__(256,5) ->
//      5 blocks/CU = 20 waves/CU (3.3x the resident waves).
//  (2) blend-shift pipeline: staging loads for kk+1 issue at cc=0/2,
//      blend+store at cc=1/3 -- each pending group covered by a FULL
//      phase (af+ds+8 MFMA) instead of one MFMA cluster. Static branches
//      in an unrolled cc loop keep pending regs statically indexed.
// Layout/swizzle identical to verified R10 modulo restrided constants
// (buf 8192 / cc 2048 / nt 1024). Bit-identical numerics.
// ---------------------------------------------------------------------------
__global__ __launch_bounds__(256, 5) void fused_kernel(
    const float* __restrict__ xT, const unsigned short* __restrict__ wAi,
    const unsigned int* __restrict__ pk, const float4* __restrict__ w4,
    float* __restrict__ out)
{
    __shared__ unsigned short Blds[2][4][2][512];   // 16 KB total, 8 KB/buf
    __shared__ unsigned int tpk_l[288];             // 9 kk x 32 px
    __shared__ float4 tw_l[288];

    const int tid = threadIdx.x;
    const int wv = tid >> 6;
    const int l = tid & 63;
    const int bx = blockIdx.x;
    const int S = ((bx & 7) << 8) + (bx >> 3);      // XCD banding (2048 blks)
    const int lb = S >> 9;                          // batch
    const int seg = S & 511;                        // 32-px segment
    const int y = seg >> 2;
    const int x0 = (seg & 3) << 5;
    const float* xb = xT + ((size_t)lb << 21);
    const float colf = (l >= 32) ? 1.f : 0.f;
    unsigned char* BB = (unsigned char*)&Blds[0][0][0][0];

    // ---- preload this block's tables (32 px x 9 kk) ----
    {
        const int base = ((lb * 9) << 14) + (y << 7) + x0;
        for (int e = tid; e < 288; e += 256) {
            tpk_l[e] = pk[base + ((e >> 5) << 14) + (e & 31)];
            tw_l[e]  = w4[base + ((e >> 5) << 14) + (e & 31)];
        }
    }
    __syncthreads();

    f32x4 acc[4][2];
#pragma unroll
    for (int i = 0; i < 4; ++i)
#pragma unroll
        for (int j = 0; j < 2; ++j) acc[i][j] = (f32x4){0.f, 0.f, 0.f, 0.f};

    // ---- prologue: stage kk=0 into buf 0 (2 st groups, blocking) ----
#pragma unroll
    for (int st = 0; st < 2; ++st) {
        f32x4 r0[4], r1[4];
        float cw0[4], cw1[4];
#pragma unroll
        for (int p = 0; p < 4; ++p) {
            int e = (wv << 3) + (st << 2) + p;
            unsigned int pv = tpk_l[e];
            float4 twv = tw_l[e];
            cw0[p] = fmaf(twv.y - twv.x, colf, twv.x);
            cw1[p] = fmaf(twv.w - twv.z, colf, twv.z);
            const int y0c = pv & 127, y1c = (pv >> 7) & 127, cb = pv >> 14;
            r0[p] = *(const f32x4*)(xb + ((((y0c << 7) + cb) << 7) + (l << 2)));
            r1[p] = *(const f32x4*)(xb + ((((y1c << 7) + cb) << 7) + (l << 2)));
        }
#pragma unroll
        for (int p = 0; p < 4; ++p) {
            float res[4];
#pragma unroll
            for (int j = 0; j < 4; ++j) {
                float t = r0[p][j] * cw0[p] + r1[p][j] * cw1[p];
                res[j] = t + __shfl_xor(t, 32);
            }
            unsigned int d0, d1;
            asm("v_cvt_pk_bf16_f32 %0, %1, %2" : "=v"(d0) : "v"(res[0]), "v"(res[1]));
            asm("v_cvt_pk_bf16_f32 %0, %1, %2" : "=v"(d1) : "v"(res[2]), "v"(res[3]));
            if (l < 32) {
                int q  = (l >> 1) & 3;
                int h  = l & 1;
                int cw = l >> 3;
                int pxg = (wv << 3) + (st << 2) + p;
                int off = cw * 2048 + (pxg >> 4) * 1024 +
                          ((((q << 8) + ((pxg & 15) << 4) + (h << 3)) ^
                            ((q << 5) ^ ((cw & 1) << 4))));
                uint2 dd; dd.x = d0; dd.y = d1;
                *(uint2*)(BB + off) = dd;
            }
        }
    }
    __syncthreads();

    // ---- main loop ----
#pragma unroll 1
    for (int kk = 0; kk < 9; ++kk) {
        const int buf = kk & 1;
        const int nbo = (buf ^ 1) * 8192;           // 8 KB per-buffer stride
        f32x4 pr0[4], pr1[4];
        float pcw0[4], pcw1[4];
#pragma unroll
        for (int cc = 0; cc < 4; ++cc) {
            // A fragments (oldest in vmcnt order)
            const unsigned short* ap =
                wAi + (((kk << 2) + cc) << 13) + (wv << 11) + (l << 3);
            short8 af[4];
#pragma unroll
            for (int mt = 0; mt < 4; ++mt)
                af[mt] = *(const short8*)(ap + (mt << 9));
            // B fragments from LDS (swizzled)
            short8 bfr[2];
            {
                int ro = ((((l >> 4) << 8) + ((l & 15) << 4)) ^
                          (((l >> 4) << 5) ^ ((cc & 1) << 4)));
                const unsigned char* rb = BB + buf * 8192 + cc * 2048 + ro;
                bfr[0] = *(const short8*)(rb);
                bfr[1] = *(const short8*)(rb + 1024);
            }
            // issue staging loads at cc=0 (st=0) and cc=2 (st=1)
            if (kk < 8 && (cc & 1) == 0) {
                const int st = cc >> 1;
#pragma unroll
                for (int p = 0; p < 4; ++p) {
                    int e = ((kk + 1) << 5) + (wv << 3) + (st << 2) + p;
                    unsigned int pv = tpk_l[e];
                    float4 twv = tw_l[e];
                    pcw0[p] = fmaf(twv.y - twv.x, colf, twv.x);
                    pcw1[p] = fmaf(twv.w - twv.z, colf, twv.z);
                    const int y0c = pv & 127, y1c = (pv >> 7) & 127, cb = pv >> 14;
                    pr0[p] = *(const f32x4*)(xb + ((((y0c << 7) + cb) << 7) + (l << 2)));
                    pr1[p] = *(const f32x4*)(xb + ((((y1c << 7) + cb) << 7) + (l << 2)));
                }
            }
            // MFMA cluster
            __builtin_amdgcn_s_setprio(1);
#pragma unroll
            for (int mt = 0; mt < 4; ++mt)
#pragma unroll
                for (int nt = 0; nt < 2; ++nt)
                    acc[mt][nt] = __builtin_amdgcn_mfma_f32_16x16x32_bf16(
                        af[mt], bfr[nt], acc[mt][nt], 0, 0, 0);
            __builtin_amdgcn_s_setprio(0);
            // blend + swizzled store at cc=1 (st=0) and cc=3 (st=1)
            if (kk < 8 && (cc & 1) == 1) {
                const int st = cc >> 1;
#pragma unroll
                for (int p = 0; p < 4; ++p) {
                    float res[4];
#pragma unroll
                    for (int j = 0; j < 4; ++j) {
                        float t = pr0[p][j] * pcw0[p] + pr1[p][j] * pcw1[p];
                        res[j] = t + __shfl_xor(t, 32);
                    }
                    unsigned int d0, d1;
                    asm("v_cvt_pk_bf16_f32 %0, %1, %2" : "=v"(d0) : "v"(res[0]), "v"(res[1]));
                    asm("v_cvt_pk_bf16_f32 %0, %1, %2" : "=v"(d1) : "v"(res[2]), "v"(res[3]));
                    if (l < 32) {
                        int q  = (l >> 1) & 3;
                        int h  = l & 1;
                        int cw = l >> 3;
                        int pxg = (wv << 3) + (st << 2) + p;
                        int off = nbo + cw * 2048 + (pxg >> 4) * 1024 +
                                  ((((q << 8) + ((pxg & 15) << 4) + (h << 3)) ^
                                    ((q << 5) ^ ((cw & 1) << 4))));
                        uint2 dd; dd.x = d0; dd.y = d1;
                        *(uint2*)(BB + off) = dd;
                    }
                }
            }
        }
        __syncthreads();
    }

    // epilogue: C/D col=lane&15 (=px), row=(lane>>4)*4+reg (verified R2-R4)
    const int crow = (l >> 4) * 4;
#pragma unroll
    for (int mt = 0; mt < 4; ++mt) {
#pragma unroll
        for (int nt = 0; nt < 2; ++nt) {
#pragma unroll
            for (int r = 0; r < 4; ++r) {
                int o = (wv << 6) + mt * 16 + crow + r;
                int pxl = (seg << 5) + nt * 16 + (l & 15);
                out[(((size_t)(lb * COUT + o)) << 14) + pxl] =
                    acc[mt][nt][r];
            }
        }
    }
}

// ---------------------------------------------------------------------------
extern "C" void kernel_launch(void* const* d_in, const int* in_sizes, int n_in,
                              void* d_out, int out_size, void* d_ws, size_t ws_size,
                              hipStream_t stream)
{
    const float* x    = (const float*)d_in[0];
    const float* offw = (const float*)d_in[1];
    const float* offb = (const float*)d_in[2];
    const float* modw = (const float*)d_in[3];
    const float* modb = (const float*)d_in[4];
    const float* wgt  = (const float*)d_in[5];
    float* out = (float*)d_out;

    char* wsb = (char*)d_ws;
    unsigned int*   pkp = (unsigned int*)wsb;                      //  2,359,296 B
    float4*         w4p = (float4*)(wsb + 2359296);                //  9,437,184 B
    unsigned short* wAi = (unsigned short*)(wsb + 11796480);       //    589,824 B
    unsigned short* wCi = (unsigned short*)(wsb + 12386304);       //     73,728 B
    float*          xTp = (float*)(wsb + 12460032);                // 33,554,432 B

    prep_kernel<<<dim3(3344), 256, 0, stream>>>(
        x, wgt, offw, modw, xTp, wAi, wCi);
    convtab_kernel<<<dim3(NB * HH), 256, 0, stream>>>(
        xTp, wCi, offb, modb, pkp, w4p);
    fused_kernel<<<dim3(NB * 512), 256, 0, stream>>>(
        xTp, wAi, pkp, w4p, out);
}

// Round 12
// 230.411 us; speedup vs baseline: 2.3246x; 2.3246x over previous
//
#include <hip/hip_runtime.h>
#include <hip/hip_bf16.h>
#include <math.h>

#define CIN 128
#define HH 128
#define WW 128
#define HWX (HH*WW)
#define COUT 256
#define NB 4

typedef __attribute__((ext_vector_type(8))) short short8;
typedef __attribute__((ext_vector_type(4))) float f32x4;
typedef __attribute__((ext_vector_type(8))) unsigned short ushort8;

__device__ __forceinline__ unsigned short f2bf(float f) {
    union { float f; unsigned int u; } c; c.f = f;
    unsigned int u = c.u + 0x7FFF + ((c.u >> 16) & 1);   // RNE
    return (unsigned short)(u >> 16);
}

// ---------------------------------------------------------------------------
// Prep (merged: xt + wimg + wcimg). [R10 verbatim]
// Block roles by blockIdx: [0,2048) xt, [2048,3200) wimg, [3200,3344) wcimg.
// ---------------------------------------------------------------------------
__global__ __launch_bounds__(256) void prep_kernel(
    const float* __restrict__ x, const float* __restrict__ wgt,
    const float* __restrict__ offw, const float* __restrict__ modw,
    float* __restrict__ xT, unsigned short* __restrict__ wAi,
    unsigned short* __restrict__ wCi)
{
    const int tid = threadIdx.x;
    const int bxg = blockIdx.x;

    if (bxg < 2048) {
        __shared__ float ls[32][132];
        const int bz = bxg;                   // b*512 + y*4 + cg
        const int cg = bz & 3;
        const int y  = (bz >> 2) & 127;
        const int b  = bz >> 9;
        {
            int c  = tid >> 3;                // 0..31
            int x0 = (tid & 7) << 4;
            const float* src = x + (((size_t)(b * CIN + (cg << 5) + c)) << 14) + (y << 7) + x0;
#pragma unroll
            for (int k = 0; k < 4; ++k)
                *(f32x4*)&ls[c][x0 + 4 * k] = *(const f32x4*)(src + 4 * k);
        }
        __syncthreads();
        {
            int xc = tid >> 1;
            int h  = tid & 1;
            float v[16];
#pragma unroll
            for (int j = 0; j < 16; ++j) v[j] = ls[h * 16 + j][xc];
            float* dst = xT + ((((size_t)((b << 7) + y) << 7) + xc) << 7) + (cg << 5) + (h << 4);
#pragma unroll
            for (int k = 0; k < 4; ++k) {
                f32x4 t = { v[4 * k], v[4 * k + 1], v[4 * k + 2], v[4 * k + 3] };
                *(f32x4*)(dst + 4 * k) = t;
            }
        }
    } else if (bxg < 3200) {
        int i = (bxg - 2048) * 256 + tid;     // < 294912
        int j  = i & 7;
        int l  = (i >> 3) & 63;
        int mt = (i >> 9) & 15;
        int cc = (i >> 13) & 3;
        int kk = i >> 15;
        int o = mt * 16 + (l & 15);
        int c = cc * 32 + (l >> 4) * 8 + j;
        wAi[i] = f2bf(wgt[(o * CIN + c) * 9 + kk]);
    } else {
        int i = (bxg - 3200) * 256 + tid;     // < 36864
        if (i < 36864) {
            int j   = i & 7;
            int l   = (i >> 3) & 63;
            int mt  = (i >> 9) & 1;
            int q36 = i >> 10;
            int o = mt * 16 + (l & 15);
            int c = ((q36 & 3) << 5) + ((l >> 4) << 3) + j;
            int t = q36 >> 2;
            float v = 0.f;
            if (o < 18)      v = offw[(o * CIN + c) * 9 + t];
            else if (o < 27) v = modw[((o - 18) * CIN + c) * 9 + t];
            wCi[i] = f2bf(v);
        }
    }
}

// ---------------------------------------------------------------------------
// Kernel CT: implicit-GEMM offset/mod conv + fused sampling tables.
// [R10 verbatim -- verified]
// ---------------------------------------------------------------------------
__global__ __launch_bounds__(256) void convtab_kernel(
    const float* __restrict__ xT, const unsigned short* __restrict__ wCi,
    const float* __restrict__ offb, const float* __restrict__ modb,
    unsigned int* __restrict__ pk_out, float4* __restrict__ w4_out)
{
    __shared__ float outs[4][32][33];
    const int tid = threadIdx.x;
    const int wave = tid >> 6;
    const int l = tid & 63;
    const int bid = blockIdx.x;               // b*128 + y
    const int b = bid >> 7;
    const int y = bid & 127;
    const int x0 = wave << 5;
    const float* xb = xT + ((size_t)b << 21);

    f32x4 acc[2][2];
#pragma unroll
    for (int i = 0; i < 2; ++i)
#pragma unroll
        for (int j = 0; j < 2; ++j) acc[i][j] = (f32x4){0.f, 0.f, 0.f, 0.f};

    const int lp = l & 15;
    const int q8 = (l >> 4) << 3;

#pragma unroll 1
    for (int q36 = 0; q36 < 36; ++q36) {
        const int t  = q36 >> 2;
        const int c0 = (q36 & 3) << 5;
        const int ty = t / 3, tx = t - 3 * ty;
        const int yp = y + ty - 1;
        if (yp < 0 || yp >= HH) continue;     // wave-uniform skip

        const unsigned short* ap = wCi + (q36 << 10) + (l << 3);
        short8 af0 = *(const short8*)(ap);
        short8 af1 = *(const short8*)(ap + 512);

        short8 bf[2];
#pragma unroll
        for (int nt = 0; nt < 2; ++nt) {
            int xp = x0 + nt * 16 + lp + tx - 1;
            bool xin = (xp >= 0) && (xp < WW);
            const float* src = xb +
                ((((yp << 7) + (xin ? xp : 0)) << 7) + c0 + q8);
            f32x4 z = {0.f, 0.f, 0.f, 0.f};
            f32x4 lo = xin ? *(const f32x4*)src : z;
            f32x4 hi = xin ? *(const f32x4*)(src + 4) : z;
            union { unsigned int u[4]; short8 s8; } cv;
            asm("v_cvt_pk_bf16_f32 %0, %1, %2" : "=v"(cv.u[0]) : "v"(lo[0]), "v"(lo[1]));
            asm("v_cvt_pk_bf16_f32 %0, %1, %2" : "=v"(cv.u[1]) : "v"(lo[2]), "v"(lo[3]));
            asm("v_cvt_pk_bf16_f32 %0, %1, %2" : "=v"(cv.u[2]) : "v"(hi[0]), "v"(hi[1]));
            asm("v_cvt_pk_bf16_f32 %0, %1, %2" : "=v"(cv.u[3]) : "v"(hi[2]), "v"(hi[3]));
            bf[nt] = cv.s8;
        }
        acc[0][0] = __builtin_amdgcn_mfma_f32_16x16x32_bf16(af0, bf[0], acc[0][0], 0, 0, 0);
        acc[1][0] = __builtin_amdgcn_mfma_f32_16x16x32_bf16(af1, bf[0], acc[1][0], 0, 0, 0);
        acc[0][1] = __builtin_amdgcn_mfma_f32_16x16x32_bf16(af0, bf[1], acc[0][1], 0, 0, 0);
        acc[1][1] = __builtin_amdgcn_mfma_f32_16x16x32_bf16(af1, bf[1], acc[1][1], 0, 0, 0);
    }

    float (*po)[33] = outs[wave];
#pragma unroll
    for (int mt = 0; mt < 2; ++mt)
#pragma unroll
        for (int nt = 0; nt < 2; ++nt)
#pragma unroll
            for (int r = 0; r < 4; ++r)
                po[nt * 16 + lp][mt * 16 + (l >> 4) * 4 + r] = acc[mt][nt][r];

    const int pxe = l & 31;
    const int xw = x0 + pxe;
    const float* pe = &outs[wave][pxe][0];
#pragma unroll 1
    for (int kk = (l >> 5); kk < 9; kk += 2) {
        float oy = pe[2 * kk]     + offb[2 * kk];
        float ox = pe[2 * kk + 1] + offb[2 * kk + 1];
        float mt_ = pe[18 + kk]   + modb[kk];

        float m = 2.f / (1.f + expf(-mt_));
        float py = (float)(y - 1 + kk / 3) + oy;
        float px = (float)(xw - 1 + kk % 3) + ox;
        float y0f = floorf(py), x0f = floorf(px);
        float wy = py - y0f, wx = px - x0f;
        int y0 = (int)y0f, x0i = (int)x0f;
        int y1 = y0 + 1, x1 = x0i + 1;
        float vy0 = (y0 >= 0 && y0 < HH) ? 1.f : 0.f;
        float vy1 = (y1 >= 0 && y1 < HH) ? 1.f : 0.f;
        float vx0 = (x0i >= 0 && x0i < WW) ? 1.f : 0.f;
        float vx1 = (x1 >= 0 && x1 < WW) ? 1.f : 0.f;
        float a  = m * (1.f - wy) * vy0;
        float bb = m * wy * vy1;
        float u  = (1.f - wx) * vx0;
        float vv = wx * vx1;
        int y0c = min(max(y0, 0), HH - 1), y1c = min(max(y1, 0), HH - 1);
        int x0c = min(max(x0i, 0), WW - 1), x1c = min(max(x1, 0), WW - 1);
        int cb = min(max(x0i, 0), WW - 2);
        float wl = ((x0c == cb) ? u : 0.f) + ((x1c == cb) ? vv : 0.f);
        float wr = ((x0c == cb + 1) ? u : 0.f) + ((x1c == cb + 1) ? vv : 0.f);
        unsigned int pkv = (unsigned)y0c | ((unsigned)y1c << 7) |
                           ((unsigned)cb << 14);
        int gid = ((b * 9 + kk) << 14) + (y << 7) + xw;
        pk_out[gid] = pkv;
        w4_out[gid] = make_float4(a * wl, a * wr, bb * wl, bb * wr);
    }
}

// ---------------------------------------------------------------------------
// Kernel F (R12 = R10 geometry + latency-only pipeline fixes).
// R11 lesson: L2 residency >> occupancy -- 64-px blocks, 1024 grid, 2
// blocks/CU kept (FETCH must stay ~28 MB). R10's ~2000 stall cyc/phase
// attacked by scheduling only:
//  (1) af double-buffer prefetch: A-fragments for phase cc+1 issued during
//      phase cc (afA/afB parity, statically indexed) -> MFMA never waits
//      on af L2 latency.
//  (2) blend-shift: staging group cc (for kk+1) issues at phase cc, blends
//      at phase cc+1 (group 3 in the tail) -> pending loads covered by a
//      FULL phase instead of one MFMA cluster. Pending regs in A/B parity
//      sets, all indices static (unrolled cc).
// Arithmetic, LDS layout/swizzle, grid, banding identical to R10.
// ---------------------------------------------------------------------------
__global__ __launch_bounds__(256, 2) void fused_kernel(
    const float* __restrict__ xT, const unsigned short* __restrict__ wAi,
    const unsigned int* __restrict__ pk, const float4* __restrict__ w4,
    float* __restrict__ out)
{
    __shared__ unsigned short Blds[2][4][4][512];   // 32 KB total, 16 KB/buf
    __shared__ unsigned int tpk_l[576];             // 9 kk x 64 px
    __shared__ float4 tw_l[576];

    const int tid = threadIdx.x;
    const int wv = tid >> 6;
    const int l = tid & 63;
    const int bx = blockIdx.x;
    const int S = ((bx & 7) << 7) + (bx >> 3);      // XCD banding (1024 blks)
    const int lb = S >> 8;                          // batch
    const int seg = S & 255;
    const int y = seg >> 1;
    const int x0 = (seg & 1) << 6;
    const float* xb = xT + ((size_t)lb << 21);
    const float colf = (l >= 32) ? 1.f : 0.f;
    unsigned char* BB = (unsigned char*)&Blds[0][0][0][0];

    // ---- preload this block's tables (64 px x 9 kk) ----
    {
        const int base = ((lb * 9) << 14) + (y << 7) + x0;
        for (int e = tid; e < 576; e += 256) {
            tpk_l[e] = pk[base + ((e >> 6) << 14) + (e & 63)];
            tw_l[e]  = w4[base + ((e >> 6) << 14) + (e & 63)];
        }
    }
    __syncthreads();

    f32x4 acc[4][4];
#pragma unroll
    for (int i = 0; i < 4; ++i)
#pragma unroll
        for (int j = 0; j < 4; ++j) acc[i][j] = (f32x4){0.f, 0.f, 0.f, 0.f};

    // ---- prologue: stage kk=0 into buf 0 ----
#pragma unroll
    for (int st = 0; st < 4; ++st) {
        f32x4 r0[4], r1[4];
        float cw0[4], cw1[4];
#pragma unroll
        for (int p = 0; p < 4; ++p) {
            int e = (wv << 4) + (st << 2) + p;
            unsigned int pv = tpk_l[e];
            float4 twv = tw_l[e];
            cw0[p] = fmaf(twv.y - twv.x, colf, twv.x);
            cw1[p] = fmaf(twv.w - twv.z, colf, twv.z);
            const int y0c = pv & 127, y1c = (pv >> 7) & 127, cb = pv >> 14;
            r0[p] = *(const f32x4*)(xb + ((((y0c << 7) + cb) << 7) + (l << 2)));
            r1[p] = *(const f32x4*)(xb + ((((y1c << 7) + cb) << 7) + (l << 2)));
        }
#pragma unroll
        for (int p = 0; p < 4; ++p) {
            float res[4];
#pragma unroll
            for (int j = 0; j < 4; ++j) {
                float t = r0[p][j] * cw0[p] + r1[p][j] * cw1[p];
                res[j] = t + __shfl_xor(t, 32);
            }
            unsigned int d0, d1;
            asm("v_cvt_pk_bf16_f32 %0, %1, %2" : "=v"(d0) : "v"(res[0]), "v"(res[1]));
            asm("v_cvt_pk_bf16_f32 %0, %1, %2" : "=v"(d1) : "v"(res[2]), "v"(res[3]));
            if (l < 32) {
                int q  = (l >> 1) & 3;
                int h  = l & 1;
                int cw = l >> 3;
                int pxg = (st << 2) + p;
                int off = cw * 4096 + wv * 1024 +
                          (((q << 8) + (pxg << 4) + (h << 3)) ^
                           ((q << 5) ^ ((cw & 1) << 4)));
                uint2 dd; dd.x = d0; dd.y = d1;
                *(uint2*)(BB + off) = dd;
            }
        }
    }
    // ---- prologue: af for (kk=0, cc=0) into afA ----
    short8 afA[4], afB[4];
    {
        const unsigned short* ap = wAi + (wv << 11) + (l << 3);
#pragma unroll
        for (int mt = 0; mt < 4; ++mt)
            afA[mt] = *(const short8*)(ap + (mt << 9));
    }
    __syncthreads();

    // ---- main loop ----
#pragma unroll 1
    for (int kk = 0; kk < 9; ++kk) {
        const int buf = kk & 1;
        const int nbo = (buf ^ 1) * 16384;          // 16 KB per-buffer stride
        // pending staging groups, parity A (groups 0,2) / B (groups 1,3)
        f32x4 prA0[4], prA1[4], prB0[4], prB1[4];
        float cwA0[4], cwA1[4], cwB0[4], cwB1[4];
#pragma unroll
        for (int cc = 0; cc < 4; ++cc) {
            // 1. B fragments from LDS (swizzled) -- lgkm in flight first
            short8 bfr[4];
            {
                int ro = ((((l >> 4) << 8) + ((l & 15) << 4)) ^
                          (((l >> 4) << 5) ^ ((cc & 1) << 4)));
                const unsigned char* rb = BB + buf * 16384 + cc * 4096 + ro;
#pragma unroll
                for (int nt = 0; nt < 4; ++nt)
                    bfr[nt] = *(const short8*)(rb + nt * 1024);
            }
            // 2. af prefetch for NEXT phase (parity (cc+1)&1)
            if (!(kk == 8 && cc == 3)) {
                const int nkk = (cc < 3) ? kk : kk + 1;
                const int ncc = (cc + 1) & 3;
                const unsigned short* apn =
                    wAi + (((nkk << 2) + ncc) << 13) + (wv << 11) + (l << 3);
                if ((cc & 1) == 0) {
#pragma unroll
                    for (int mt = 0; mt < 4; ++mt)
                        afB[mt] = *(const short8*)(apn + (mt << 9));
                } else {
#pragma unroll
                    for (int mt = 0; mt < 4; ++mt)
                        afA[mt] = *(const short8*)(apn + (mt << 9));
                }
            }
            // 3. issue staging group cc for kk+1 into parity cc&1
            if (kk < 8) {
#pragma unroll
                for (int p = 0; p < 4; ++p) {
                    int e = ((kk + 1) << 6) + (wv << 4) + (cc << 2) + p;
                    unsigned int pv = tpk_l[e];
                    float4 twv = tw_l[e];
                    const int y0c = pv & 127, y1c = (pv >> 7) & 127, cb = pv >> 14;
                    const float* b0 = xb + ((((y0c << 7) + cb) << 7) + (l << 2));
                    const float* b1 = xb + ((((y1c << 7) + cb) << 7) + (l << 2));
                    if ((cc & 1) == 0) {
                        cwA0[p] = fmaf(twv.y - twv.x, colf, twv.x);
                        cwA1[p] = fmaf(twv.w - twv.z, colf, twv.z);
                        prA0[p] = *(const f32x4*)b0;
                        prA1[p] = *(const f32x4*)b1;
                    } else {
                        cwB0[p] = fmaf(twv.y - twv.x, colf, twv.x);
                        cwB1[p] = fmaf(twv.w - twv.z, colf, twv.z);
                        prB0[p] = *(const f32x4*)b0;
                        prB1[p] = *(const f32x4*)b1;
                    }
                }
            }
            // 4. MFMA cluster (uses af parity cc&1 -- loaded LAST phase)
            __builtin_amdgcn_s_setprio(1);
            if ((cc & 1) == 0) {
#pragma unroll
                for (int mt = 0; mt < 4; ++mt)
#pragma unroll
                    for (int nt = 0; nt < 4; ++nt)
                        acc[mt][nt] = __builtin_amdgcn_mfma_f32_16x16x32_bf16(
                            afA[mt], bfr[nt], acc[mt][nt], 0, 0, 0);
            } else {
#pragma unroll
                for (int mt = 0; mt < 4; ++mt)
#pragma unroll
                    for (int nt = 0; nt < 4; ++nt)
                        acc[mt][nt] = __builtin_amdgcn_mfma_f32_16x16x32_bf16(
                            afB[mt], bfr[nt], acc[mt][nt], 0, 0, 0);
            }
            __builtin_amdgcn_s_setprio(0);
            // 5. blend group cc-1 (issued a FULL phase ago), swizzled store
            if (kk < 8 && cc >= 1) {
                const int g = cc - 1;               // parity g&1
#pragma unroll
                for (int p = 0; p < 4; ++p) {
                    float res[4];
#pragma unroll
                    for (int j = 0; j < 4; ++j) {
                        float t = ((g & 1) == 0)
                            ? prA0[p][j] * cwA0[p] + prA1[p][j] * cwA1[p]
                            : prB0[p][j] * cwB0[p] + prB1[p][j] * cwB1[p];
                        res[j] = t + __shfl_xor(t, 32);
                    }
                    unsigned int d0, d1;
                    asm("v_cvt_pk_bf16_f32 %0, %1, %2" : "=v"(d0) : "v"(res[0]), "v"(res[1]));
                    asm("v_cvt_pk_bf16_f32 %0, %1, %2" : "=v"(d1) : "v"(res[2]), "v"(res[3]));
                    if (l < 32) {
                        int q  = (l >> 1) & 3;
                        int h  = l & 1;
                        int cw = l >> 3;
                        int pxg = (g << 2) + p;
                        int off = nbo + cw * 4096 + wv * 1024 +
                                  (((q << 8) + (pxg << 4) + (h << 3)) ^
                                   ((q << 5) ^ ((cw & 1) << 4)));
                        uint2 dd; dd.x = d0; dd.y = d1;
                        *(uint2*)(BB + off) = dd;
                    }
                }
            }
        }
        // tail: blend group 3 (parity B)
        if (kk < 8) {
#pragma unroll
            for (int p = 0; p < 4; ++p) {
                float res[4];
#pragma unroll
                for (int j = 0; j < 4; ++j) {
                    float t = prB0[p][j] * cwB0[p] + prB1[p][j] * cwB1[p];
                    res[j] = t + __shfl_xor(t, 32);
                }
                unsigned int d0, d1;
                asm("v_cvt_pk_bf16_f32 %0, %1, %2" : "=v"(d0) : "v"(res[0]), "v"(res[1]));
                asm("v_cvt_pk_bf16_f32 %0, %1, %2" : "=v"(d1) : "v"(res[2]), "v"(res[3]));
                if (l < 32) {
                    int q  = (l >> 1) & 3;
                    int h  = l & 1;
                    int cw = l >> 3;
                    int pxg = 12 + p;               // group 3
                    int off = nbo + cw * 4096 + wv * 1024 +
                              (((q << 8) + (pxg << 4) + (h << 3)) ^
                               ((q << 5) ^ ((cw & 1) << 4)));
                    uint2 dd; dd.x = d0; dd.y = d1;
                    *(uint2*)(BB + off) = dd;
                }
            }
        }
        __syncthreads();
    }

    // epilogue: C/D col=lane&15 (=px), row=(lane>>4)*4+reg (verified R2-R4)
    const int crow = (l >> 4) * 4;
    const int pxl = (seg << 6) + (l & 15);
#pragma unroll
    for (int mt = 0; mt < 4; ++mt) {
#pragma unroll
        for (int nt = 0; nt < 4; ++nt) {
#pragma unroll
            for (int r = 0; r < 4; ++r) {
                int o = wv * 64 + mt * 16 + crow + r;
                out[(((size_t)(lb * COUT + o)) << 14) + pxl + nt * 16] =
                    acc[mt][nt][r];
            }
        }
    }
}

// ---------------------------------------------------------------------------
extern "C" void kernel_launch(void* const* d_in, const int* in_sizes, int n_in,
                              void* d_out, int out_size, void* d_ws, size_t ws_size,
                              hipStream_t stream)
{
    const float* x    = (const float*)d_in[0];
    const float* offw = (const float*)d_in[1];
    const float* offb = (const float*)d_in[2];
    const float* modw = (const float*)d_in[3];
    const float* modb = (const float*)d_in[4];
    const float* wgt  = (const float*)d_in[5];
    float* out = (float*)d_out;

    char* wsb = (char*)d_ws;
    unsigned int*   pkp = (unsigned int*)wsb;                      //  2,359,296 B
    float4*         w4p = (float4*)(wsb + 2359296);                //  9,437,184 B
    unsigned short* wAi = (unsigned short*)(wsb + 11796480);       //    589,824 B
    unsigned short* wCi = (unsigned short*)(wsb + 12386304);       //     73,728 B
    float*          xTp = (float*)(wsb + 12460032);                // 33,554,432 B

    prep_kernel<<<dim3(3344), 256, 0, stream>>>(
        x, wgt, offw, modw, xTp, wAi, wCi);
    convtab_kernel<<<dim3(NB * HH), 256, 0, stream>>>(
        xTp, wCi, offb, modb, pkp, w4p);
    fused_kernel<<<dim3(NB * 256), 256, 0, stream>>>(
        xTp, wAi, pkp, w4p, out);
}